// Round 10
// baseline (954.294 us; speedup 1.0000x reference)
//
#include <hip/hip_runtime.h>
#include <math.h>

// ============================================================================
// CapsuleNet forward, round 10.
// prim MFMA: R6 structure (128x128, BK=32, 16KB LDS, XOR-swizzled conflict-
//   free coalesced staging) + split-K 4 -> 1152 blocks = 4.5/CU (90% tail
//   balance vs R6's 2.25/CU = 75%).
// decoder: fc1+fc2+fc3 fused into ONE kernel (4 batch rows/block, weights
//   from L2, intermediates in LDS) -- removes 2 launches + HBM round-trips.
// conv1: 4x oy-split (R9). squash: 4-slice. wtrans/priors/routing/classes
//   as R6.
// ============================================================================

typedef _Float16 f16;
typedef _Float16 f16x8 __attribute__((ext_vector_type(8)));
typedef _Float16 f16x4 __attribute__((ext_vector_type(4)));
typedef float f32x4 __attribute__((ext_vector_type(4)));

__device__ __forceinline__ void gl_lds16(const void* g, void* l) {
  __builtin_amdgcn_global_load_lds(
      (const __attribute__((address_space(1))) void*)g,
      (__attribute__((address_space(3))) void*)l, 16, 0, 0);
}

// ------- conv1: x[512,1,28,28] -> ht fp16 NHWC [512,20,20,256], 4x oy-split
__global__ __launch_bounds__(256, 2) void conv1_kernel(
    const float* __restrict__ x, const float* __restrict__ w,
    const float* __restrict__ bias, f16* __restrict__ ht)
{
  __shared__ float xs[364];           // 13 rows x 28
  const int b = blockIdx.x;
  const int y0 = blockIdx.y * 5;      // output rows y0..y0+4
  const int t = threadIdx.x;          // t == output channel (ic of ht)
  for (int i = t; i < 364; i += 256) xs[i] = x[b * 784 + y0 * 28 + i];
  float wr[81];
#pragma unroll
  for (int k = 0; k < 81; ++k) wr[k] = w[t * 81 + k];
  const float bv = bias[t];
  __syncthreads();
  for (int oy = y0; oy < y0 + 5; ++oy) {
    float acc[20];
#pragma unroll
    for (int i = 0; i < 20; ++i) acc[i] = bv;
#pragma unroll
    for (int ky = 0; ky < 9; ++ky) {
      float xr[28];
#pragma unroll
      for (int q = 0; q < 7; ++q) {
        const float4 v = *(const float4*)&xs[(oy - y0 + ky) * 28 + q * 4];
        xr[q*4+0] = v.x; xr[q*4+1] = v.y; xr[q*4+2] = v.z; xr[q*4+3] = v.w;
      }
#pragma unroll
      for (int kx = 0; kx < 9; ++kx) {
        const float wv = wr[ky * 9 + kx];
#pragma unroll
        for (int ox = 0; ox < 20; ++ox) acc[ox] = fmaf(xr[ox + kx], wv, acc[ox]);
      }
    }
    f16* hp = &ht[(size_t)((b * 20 + oy) * 20) * 256 + t];
#pragma unroll
    for (int ox = 0; ox < 20; ++ox)
      hp[ox * 256] = (f16)fmaxf(acc[ox], 0.f);
  }
}

// --------- wtrans: prim_w fp32 [oc][ic][kykx] -> wt fp16 [oc][kykx][ic] ----
__global__ __launch_bounds__(256) void wtrans_kernel(
    const float* __restrict__ w, f16* __restrict__ wt)
{
  __shared__ float tile[64 * 83];
  const int oc = blockIdx.x;
  const int icq = blockIdx.y;
  const int t = threadIdx.x;
  const float* src = w + (size_t)oc * 20736 + (size_t)icq * 64 * 81;
  for (int idx = t; idx < 5184; idx += 256) {
    const int ici = idx / 81, kk = idx - ici * 81;
    tile[ici * 83 + kk] = src[idx];
  }
  __syncthreads();
  f16* dst = wt + (size_t)oc * 20736 + icq * 64;
  for (int idx = t; idx < 5184; idx += 256) {
    const int kk = idx >> 6, ici = idx & 63;
    dst[kk * 256 + ici] = (f16)tile[ici * 83 + kk];
  }
}

// ---------------- primary caps conv: MFMA implicit GEMM --------------------
// 1152 blocks = 144 mb x 2 nb x 4 ks (id&7 = mb low bits). 4 waves, wave
// tile 64x64, BK=32, 16KB LDS. Staging: 4 lanes per row's 64B k-run,
// XORed chunk (lane&3)^((lane>>3)&3); consumer qx = quad^((lrow>>1)&3)
// -> measured conflict-free (R6).
__global__ __launch_bounds__(256) void prim_mfma_kernel(
    const f16* __restrict__ ht, const f16* __restrict__ wt,
    float* __restrict__ part)
{
  __shared__ f16 sm[8192];            // As[0..4096) | Bs[4096..8192), 16 KB
  const int t = threadIdx.x;
  const int wv = t >> 6, lane = t & 63;
  const int id = blockIdx.x;
  const int g = id >> 3;              // [0,144)
  const int ks = g & 3;
  const int nb = (g >> 2) & 1;
  const int mb = (id & 7) + 8 * (g >> 3);
  const int m0 = mb * 128, n0 = nb * 128;

  const int chunk = (lane & 3) ^ ((lane >> 3) & 3);
  long aoff[2], boff[2];
#pragma unroll
  for (int i = 0; i < 2; ++i) {
    const int r = wv * 32 + i * 16 + (lane >> 2);  // local row in tile
    const int m = m0 + r;
    const int b = m / 36, pos = m - b * 36;
    const int oy = pos / 6, ox = pos - oy * 6;
    aoff[i] = (long)(((b * 20 + 2 * oy) * 20 + 2 * ox) * 256) * 2 + chunk * 16;
    boff[i] = (long)(n0 + r) * 41472 + chunk * 16;   // oc*81*256*2
  }
  const char* htc = (const char*)ht;
  const char* wtc = (const char*)wt;

  const int lrow = lane & 15, quad = lane >> 4;
  const int qx = quad ^ ((lrow >> 1) & 3);
  const int wm = wv & 1, wn = wv >> 1;
  f32x4 acc[4][4] = {};

  const int s0 = ks * 162, s1 = s0 + 162;   // 648 BK=32 stages over 4 ks
  for (int s = s0; s < s1; ++s) {
    const int kykx = s >> 3, icb = s & 7;
    const int ky = kykx / 9, kx = kykx - ky * 9;
    const long astep = (long)((((ky * 20 + kx) * 256) + icb * 32) * 2);
    const long bstep = (long)(((kykx * 256) + icb * 32) * 2);
    __syncthreads();
    {
      char* dA = (char*)sm + wv * 2048;
      char* dB = (char*)sm + 8192 + wv * 2048;
      gl_lds16(htc + aoff[0] + astep, dA);
      gl_lds16(htc + aoff[1] + astep, dA + 1024);
      gl_lds16(wtc + boff[0] + bstep, dB);
      gl_lds16(wtc + boff[1] + bstep, dB + 1024);
    }
    __syncthreads();
    const f16* As = sm;
    const f16* Bs = sm + 4096;
    f16x8 af[4], bf[4];
#pragma unroll
    for (int mt = 0; mt < 4; ++mt)
      af[mt] = *(const f16x8*)&As[(wm * 64 + mt * 16 + lrow) * 32 + qx * 8];
#pragma unroll
    for (int nt = 0; nt < 4; ++nt)
      bf[nt] = *(const f16x8*)&Bs[(wn * 64 + nt * 16 + lrow) * 32 + qx * 8];
#pragma unroll
    for (int mt = 0; mt < 4; ++mt)
#pragma unroll
      for (int nt = 0; nt < 4; ++nt)
        acc[mt][nt] = __builtin_amdgcn_mfma_f32_16x16x32_f16(
            af[mt], bf[nt], acc[mt][nt], 0, 0, 0);
  }

  // epilogue: partials [m][col'] with col' = (oc&31)*8 + oc>>5 (squash reads
  // its 8 values oc = i*32+cc contiguously).
  float* pp = part + (size_t)ks * 4718592;
#pragma unroll
  for (int mt = 0; mt < 4; ++mt) {
    const int mbase = m0 + wm * 64 + mt * 16 + quad * 4;  // row=quad*4+reg
#pragma unroll
    for (int nt = 0; nt < 4; ++nt) {
      const int n = n0 + wn * 64 + nt * 16 + lrow;        // col=lane&15
      const int np = (n & 31) * 8 + (n >> 5);
#pragma unroll
      for (int rg = 0; rg < 4; ++rg)
        pp[(size_t)(mbase + rg) * 256 + np] = acc[mt][nt][rg];
    }
  }
}

// --------- split-K(4) reduce + bias + squash -> u[512,1152,8] fp32 ---------
__global__ void squash_kernel(const float* __restrict__ part,
                              const float* __restrict__ bias,
                              float* __restrict__ u)
{
  const int tid = blockIdx.x * 256 + threadIdx.x;   // (b*36+pos)*32 + cc
  if (tid >= 512 * 36 * 32) return;
  const int cc = tid & 31;
  const int row = tid >> 5;                         // b*36 + pos
  const int b = row / 36;
  const int pos = row - b * 36;
  const float* p = part + (size_t)row * 256 + cc * 8;
  float v[8] = {};
#pragma unroll
  for (int ksl = 0; ksl < 4; ++ksl) {
    const float4 a0 = *(const float4*)(p + (size_t)ksl * 4718592);
    const float4 a1 = *(const float4*)(p + (size_t)ksl * 4718592 + 4);
    v[0] += a0.x; v[1] += a0.y; v[2] += a0.z; v[3] += a0.w;
    v[4] += a1.x; v[5] += a1.y; v[6] += a1.z; v[7] += a1.w;
  }
  float sq = 0.f;
#pragma unroll
  for (int i = 0; i < 8; ++i) {
    v[i] += bias[i * 32 + cc];
    sq = fmaf(v[i], v[i], sq);
  }
  const float scale = sq / ((1.f + sq) * sqrtf(sq));
  float* up = &u[(size_t)(b * 1152 + cc * 36 + pos) * 8];
#pragma unroll
  for (int i = 0; i < 8; ++i) up[i] = v[i] * scale;
}

// --------- priors: P[c,b,r,16] fp16 = einsum('bri,crio') -------------------
__global__ __launch_bounds__(256, 4) void priors_kernel(
    const float* __restrict__ u, const float* __restrict__ rw,
    f16* __restrict__ P)
{
  const int t = threadIdx.x;
  const int rl = t >> 2, oq = t & 3;
  const int r = blockIdx.x * 64 + rl;
  const int b0 = blockIdx.y * 64;
  const int c = blockIdx.z;

  float4 wreg[8];
  const float* wbase = rw + (size_t)(c * 1152 + r) * 128 + oq * 4;
#pragma unroll
  for (int k = 0; k < 8; ++k)
    wreg[k] = *(const float4*)(wbase + k * 16);

  f16* pbase = P + (size_t)((c * 512 + b0) * 1152 + r) * 16 + oq * 4;
  const float* ubase = u + (size_t)(b0 * 1152 + r) * 8;

  for (int b = 0; b < 64; ++b) {
    const float4 ua = *(const float4*)(ubase + (size_t)b * 9216);
    const float4 ub = *(const float4*)(ubase + (size_t)b * 9216 + 4);
    const float uu[8] = {ua.x, ua.y, ua.z, ua.w, ub.x, ub.y, ub.z, ub.w};
    float ax = 0.f, ay = 0.f, az = 0.f, aw = 0.f;
#pragma unroll
    for (int k = 0; k < 8; ++k) {
      ax = fmaf(uu[k], wreg[k].x, ax);
      ay = fmaf(uu[k], wreg[k].y, ay);
      az = fmaf(uu[k], wreg[k].z, az);
      aw = fmaf(uu[k], wreg[k].w, aw);
    }
    f16x4 st;
    st[0] = (f16)ax; st[1] = (f16)ay; st[2] = (f16)az; st[3] = (f16)aw;
    *(f16x4*)(pbase + (size_t)b * 18432) = st;
  }
}

// ---------------- dynamic routing, one block per (c,b) ---------------------
__device__ __forceinline__ float wave_sum(float v) {
#pragma unroll
  for (int off = 32; off > 0; off >>= 1) v += __shfl_xor(v, off);
  return v;
}
__device__ __forceinline__ float wave_max(float v) {
#pragma unroll
  for (int off = 32; off > 0; off >>= 1) v = fmaxf(v, __shfl_xor(v, off));
  return v;
}

__global__ __launch_bounds__(256, 2) void routing_kernel(
    const f16* __restrict__ Pg, float* __restrict__ caps)
{
  const int c = blockIdx.x >> 9;
  const int b = blockIdx.x & 511;
  const int t = threadIdx.x;
  const int wid = t >> 6;
  const int lane = t & 63;
  __shared__ float xred[4 * 17];

  float P[5][16];
  float lg[5];
  const int nk = (t < 128) ? 5 : 4;
#pragma unroll
  for (int k = 0; k < 5; ++k)
#pragma unroll
    for (int o = 0; o < 16; ++o) P[k][o] = 0.f;

  const f16* pbase = Pg + (size_t)((c * 512 + b) * 1152) * 16;
#pragma unroll
  for (int k = 0; k < 5; ++k) {
    if (k < nk) {
      const int r = t + (k << 8);
      const f16x8 p0 = *(const f16x8*)&pbase[(size_t)r * 16];
      const f16x8 p1 = *(const f16x8*)&pbase[(size_t)r * 16 + 8];
#pragma unroll
      for (int o = 0; o < 8; ++o) {
        P[k][o]     = (float)p0[o];
        P[k][o + 8] = (float)p1[o];
      }
    }
  }

  float v[16];
  {
    float sq = 0.f;
#pragma unroll
    for (int o = 0; o < 16; ++o) {
      float p = 0.f;
#pragma unroll
      for (int k = 0; k < 5; ++k) p += P[k][o];
      p = wave_sum(p);
      if (lane == 0) xred[wid * 17 + o] = p;
      v[o] = 0.f;
    }
    __syncthreads();
#pragma unroll
    for (int o = 0; o < 16; ++o) {
      const float s = (xred[o] + xred[17 + o] + xred[34 + o] + xred[51 + o]) *
                      (1.f / 1152.f);
      v[o] = s;
      sq = fmaf(s, s, sq);
    }
    const float scale = sq / ((1.f + sq) * sqrtf(sq));
#pragma unroll
    for (int o = 0; o < 16; ++o) v[o] *= scale;
    __syncthreads();
  }
#pragma unroll
  for (int k = 0; k < 5; ++k) {
    float a = 0.f;
#pragma unroll
    for (int o = 0; o < 16; ++o) a = fmaf(P[k][o], v[o], a);
    lg[k] = a;
  }

  for (int it = 1; it < 3; ++it) {
    float m = -1e30f;
#pragma unroll
    for (int k = 0; k < 5; ++k) if (k < nk) m = fmaxf(m, lg[k]);
    m = wave_max(m);
    if (lane == 0) xred[wid * 17 + 16] = m;
    __syncthreads();
    const float mx = fmaxf(fmaxf(xred[16], xred[17 + 16]),
                           fmaxf(xred[34 + 16], xred[51 + 16]));
    __syncthreads();
    float e[5];
#pragma unroll
    for (int k = 0; k < 5; ++k) e[k] = (k < nk) ? expf(lg[k] - mx) : 0.f;
    float pS = 0.f;
#pragma unroll
    for (int k = 0; k < 5; ++k) pS += e[k];
    pS = wave_sum(pS);
    if (lane == 0) xred[wid * 17 + 16] = pS;
#pragma unroll
    for (int o = 0; o < 16; ++o) {
      float p = 0.f;
#pragma unroll
      for (int k = 0; k < 5; ++k) p = fmaf(e[k], P[k][o], p);
      p = wave_sum(p);
      if (lane == 0) xred[wid * 17 + o] = p;
    }
    __syncthreads();
    const float S = xred[16] + xred[17 + 16] + xred[34 + 16] + xred[51 + 16];
    const float inv = 1.f / S;
    float sq = 0.f;
#pragma unroll
    for (int o = 0; o < 16; ++o) {
      const float s = (xred[o] + xred[17 + o] + xred[34 + o] + xred[51 + o]) * inv;
      v[o] = s;
      sq = fmaf(s, s, sq);
    }
    const float scale = sq / ((1.f + sq) * sqrtf(sq));
#pragma unroll
    for (int o = 0; o < 16; ++o) v[o] *= scale;
    __syncthreads();
    if (it < 2) {
#pragma unroll
      for (int k = 0; k < 5; ++k) {
        float a = 0.f;
#pragma unroll
        for (int o = 0; o < 16; ++o) a = fmaf(P[k][o], v[o], a);
        lg[k] += a;
      }
    }
  }
  if (t == 0) {
    float* cp = &caps[(b * 10 + c) * 16];
#pragma unroll
    for (int o = 0; o < 16; ++o) cp[o] = v[o];
  }
}

// --------- classes softmax + argmax one-hot mask ---------------------------
__global__ void classes_kernel(const float* __restrict__ caps,
                               float* __restrict__ out_classes,
                               float* __restrict__ d0)
{
  const int b = blockIdx.x * 256 + threadIdx.x;
  if (b >= 512) return;
  float nrm[10];
#pragma unroll
  for (int cc = 0; cc < 10; ++cc) {
    float sq = 0.f;
#pragma unroll
    for (int o = 0; o < 16; ++o) {
      const float vv = caps[(b * 10 + cc) * 16 + o];
      sq = fmaf(vv, vv, sq);
    }
    nrm[cc] = sqrtf(sq);
  }
  float mx = nrm[0]; int cs = 0;
#pragma unroll
  for (int cc = 1; cc < 10; ++cc)
    if (nrm[cc] > mx) { mx = nrm[cc]; cs = cc; }
  float e[10], ssum = 0.f;
#pragma unroll
  for (int cc = 0; cc < 10; ++cc) { e[cc] = expf(nrm[cc] - mx); ssum += e[cc]; }
  const float inv = 1.f / ssum;
#pragma unroll
  for (int cc = 0; cc < 10; ++cc) out_classes[b * 10 + cc] = e[cc] * inv;
#pragma unroll
  for (int cc = 0; cc < 10; ++cc)
#pragma unroll
    for (int o = 0; o < 16; ++o)
      d0[b * 160 + cc * 16 + o] = (cc == cs) ? caps[(b * 10 + cc) * 16 + o] : 0.f;
}

// --------- fused decoder: d0 -> relu fc1 -> relu fc2 -> sigmoid fc3 --------
// One block = 4 batch rows; weights streamed from global (L2-resident,
// per-thread sequential row reads); intermediates in LDS (26.5 KB).
__global__ __launch_bounds__(256, 2) void decoder_kernel(
    const float* __restrict__ d0,
    const float* __restrict__ W1, const float* __restrict__ b1,
    const float* __restrict__ W2, const float* __restrict__ b2,
    const float* __restrict__ W3, const float* __restrict__ b3,
    float* __restrict__ recon)
{
  __shared__ float s0[4 * 160];
  __shared__ float s1[4 * 512];
  __shared__ float s2[4 * 1024];
  const int t = threadIdx.x;
  const int row0 = blockIdx.x * 4;

  for (int i = t; i < 640; i += 256) {
    const int r = i / 160, k = i - r * 160;
    s0[i] = d0[(row0 + r) * 160 + k];
  }
  __syncthreads();

  // layer 1: 512 outputs, K=160
#pragma unroll
  for (int j = 0; j < 2; ++j) {
    const int n = t + j * 256;
    float a0 = 0.f, a1 = 0.f, a2 = 0.f, a3 = 0.f;
    const float* wr = &W1[n * 160];
    for (int k = 0; k < 160; k += 4) {
      const float4 w = *(const float4*)&wr[k];
#pragma unroll
      for (int q = 0; q < 4; ++q) {
        const float wq = (&w.x)[q];
        a0 = fmaf(s0[k + q],       wq, a0);
        a1 = fmaf(s0[160 + k + q], wq, a1);
        a2 = fmaf(s0[320 + k + q], wq, a2);
        a3 = fmaf(s0[480 + k + q], wq, a3);
      }
    }
    const float bb = b1[n];
    s1[n]        = fmaxf(a0 + bb, 0.f);
    s1[512 + n]  = fmaxf(a1 + bb, 0.f);
    s1[1024 + n] = fmaxf(a2 + bb, 0.f);
    s1[1536 + n] = fmaxf(a3 + bb, 0.f);
  }
  __syncthreads();

  // layer 2: 1024 outputs, K=512
#pragma unroll
  for (int j = 0; j < 4; ++j) {
    const int n = t + j * 256;
    float a0 = 0.f, a1 = 0.f, a2 = 0.f, a3 = 0.f;
    const float* wr = &W2[n * 512];
    for (int k = 0; k < 512; k += 4) {
      const float4 w = *(const float4*)&wr[k];
#pragma unroll
      for (int q = 0; q < 4; ++q) {
        const float wq = (&w.x)[q];
        a0 = fmaf(s1[k + q],        wq, a0);
        a1 = fmaf(s1[512 + k + q],  wq, a1);
        a2 = fmaf(s1[1024 + k + q], wq, a2);
        a3 = fmaf(s1[1536 + k + q], wq, a3);
      }
    }
    const float bb = b2[n];
    s2[n]        = fmaxf(a0 + bb, 0.f);
    s2[1024 + n] = fmaxf(a1 + bb, 0.f);
    s2[2048 + n] = fmaxf(a2 + bb, 0.f);
    s2[3072 + n] = fmaxf(a3 + bb, 0.f);
  }
  __syncthreads();

  // layer 3: 784 outputs, K=1024, sigmoid
  for (int n = t; n < 784; n += 256) {
    float a0 = 0.f, a1 = 0.f, a2 = 0.f, a3 = 0.f;
    const float* wr = &W3[n * 1024];
    for (int k = 0; k < 1024; k += 4) {
      const float4 w = *(const float4*)&wr[k];
#pragma unroll
      for (int q = 0; q < 4; ++q) {
        const float wq = (&w.x)[q];
        a0 = fmaf(s2[k + q],        wq, a0);
        a1 = fmaf(s2[1024 + k + q], wq, a1);
        a2 = fmaf(s2[2048 + k + q], wq, a2);
        a3 = fmaf(s2[3072 + k + q], wq, a3);
      }
    }
    const float bb = b3[n];
    recon[(row0 + 0) * 784 + n] = 1.f / (1.f + expf(-(a0 + bb)));
    recon[(row0 + 1) * 784 + n] = 1.f / (1.f + expf(-(a1 + bb)));
    recon[(row0 + 2) * 784 + n] = 1.f / (1.f + expf(-(a2 + bb)));
    recon[(row0 + 3) * 784 + n] = 1.f / (1.f + expf(-(a3 + bb)));
  }
}

// ============================================================================
extern "C" void kernel_launch(void* const* d_in, const int* in_sizes, int n_in,
                              void* d_out, int out_size, void* d_ws, size_t ws_size,
                              hipStream_t stream)
{
  const float* x       = (const float*)d_in[0];
  const float* conv1_w = (const float*)d_in[1];
  const float* conv1_b = (const float*)d_in[2];
  const float* prim_w  = (const float*)d_in[3];
  const float* prim_b  = (const float*)d_in[4];
  const float* route_w = (const float*)d_in[5];
  const float* dec_w1  = (const float*)d_in[6];
  const float* dec_b1  = (const float*)d_in[7];
  const float* dec_w2  = (const float*)d_in[8];
  const float* dec_b2  = (const float*)d_in[9];
  const float* dec_w3  = (const float*)d_in[10];
  const float* dec_b3  = (const float*)d_in[11];
  float* out = (float*)d_out;

  char* ws = (char*)d_ws;
  f16*   ht   = (f16*)(ws);                        // 104,857,600 B
  f16*   wtp  = (f16*)(ws + 104857600);            //  10,616,832 B
  float* part = (float*)(ws + 115474432);          //  75,497,472 B (4 slices)
  float* u    = (float*)(ws + 190971904);          //  18,874,368 B
  f16*   P    = (f16*)(ws);                        // 188,743,680 B (overlays)
  float* caps = (float*)(ws + 209846272);          // 327,680 B
  float* d0   = (float*)(ws + 210173952);          // 327,680 B

  hipLaunchKernelGGL(conv1_kernel, dim3(512, 4), dim3(256), 0, stream,
                     x, conv1_w, conv1_b, ht);
  hipLaunchKernelGGL(wtrans_kernel, dim3(256, 4), dim3(256), 0, stream,
                     prim_w, wtp);
  hipLaunchKernelGGL(prim_mfma_kernel, dim3(1152), dim3(256), 0, stream,
                     ht, wtp, part);
  hipLaunchKernelGGL(squash_kernel, dim3(2304), dim3(256), 0, stream,
                     part, prim_b, u);
  hipLaunchKernelGGL(priors_kernel, dim3(18, 8, 10), dim3(256), 0, stream,
                     u, route_w, P);
  hipLaunchKernelGGL(routing_kernel, dim3(5120), dim3(256), 0, stream,
                     P, caps);
  hipLaunchKernelGGL(classes_kernel, dim3(2), dim3(256), 0, stream,
                     caps, out, d0);
  hipLaunchKernelGGL(decoder_kernel, dim3(128), dim3(256), 0, stream,
                     d0, dec_w1, dec_b1, dec_w2, dec_b2, dec_w3, dec_b3,
                     out + 5120);
}

// Round 11
// 799.701 us; speedup vs baseline: 1.1933x; 1.1933x over previous
//
#include <hip/hip_runtime.h>
#include <math.h>

// ============================================================================
// CapsuleNet forward, round 11.
// prim MFMA: R10 (128x128, BK=32, split-K 4, XOR-swizzled coalesced staging)
//   + DOUBLE BUFFER with R4's ordering (sync; stage next->other buf; consume)
//   -- halves barrier count and gives each vmcnt drain ~1 consume of slack.
//   (R4's regression is now attributed to its transaction-bloated staging,
//   per R5's identical result; this combination was never tested.)
// decoder: REVERTED to 3 tiled fc kernels (R10 fusion had 128x redundant
//   W2/W3 streaming -> ~700 MB traffic + a 31 ms pathological dispatch).
// conv1 4x oy-split, wtrans, squash 4-slice, priors, routing, classes as R10.
// ============================================================================

typedef _Float16 f16;
typedef _Float16 f16x8 __attribute__((ext_vector_type(8)));
typedef _Float16 f16x4 __attribute__((ext_vector_type(4)));
typedef float f32x4 __attribute__((ext_vector_type(4)));

__device__ __forceinline__ void gl_lds16(const void* g, void* l) {
  __builtin_amdgcn_global_load_lds(
      (const __attribute__((address_space(1))) void*)g,
      (__attribute__((address_space(3))) void*)l, 16, 0, 0);
}

// ------- conv1: x[512,1,28,28] -> ht fp16 NHWC [512,20,20,256], 4x oy-split
__global__ __launch_bounds__(256, 2) void conv1_kernel(
    const float* __restrict__ x, const float* __restrict__ w,
    const float* __restrict__ bias, f16* __restrict__ ht)
{
  __shared__ float xs[364];           // 13 rows x 28
  const int b = blockIdx.x;
  const int y0 = blockIdx.y * 5;      // output rows y0..y0+4
  const int t = threadIdx.x;          // t == output channel (ic of ht)
  for (int i = t; i < 364; i += 256) xs[i] = x[b * 784 + y0 * 28 + i];
  float wr[81];
#pragma unroll
  for (int k = 0; k < 81; ++k) wr[k] = w[t * 81 + k];
  const float bv = bias[t];
  __syncthreads();
  for (int oy = y0; oy < y0 + 5; ++oy) {
    float acc[20];
#pragma unroll
    for (int i = 0; i < 20; ++i) acc[i] = bv;
#pragma unroll
    for (int ky = 0; ky < 9; ++ky) {
      float xr[28];
#pragma unroll
      for (int q = 0; q < 7; ++q) {
        const float4 v = *(const float4*)&xs[(oy - y0 + ky) * 28 + q * 4];
        xr[q*4+0] = v.x; xr[q*4+1] = v.y; xr[q*4+2] = v.z; xr[q*4+3] = v.w;
      }
#pragma unroll
      for (int kx = 0; kx < 9; ++kx) {
        const float wv = wr[ky * 9 + kx];
#pragma unroll
        for (int ox = 0; ox < 20; ++ox) acc[ox] = fmaf(xr[ox + kx], wv, acc[ox]);
      }
    }
    f16* hp = &ht[(size_t)((b * 20 + oy) * 20) * 256 + t];
#pragma unroll
    for (int ox = 0; ox < 20; ++ox)
      hp[ox * 256] = (f16)fmaxf(acc[ox], 0.f);
  }
}

// --------- wtrans: prim_w fp32 [oc][ic][kykx] -> wt fp16 [oc][kykx][ic] ----
__global__ __launch_bounds__(256) void wtrans_kernel(
    const float* __restrict__ w, f16* __restrict__ wt)
{
  __shared__ float tile[64 * 83];
  const int oc = blockIdx.x;
  const int icq = blockIdx.y;
  const int t = threadIdx.x;
  const float* src = w + (size_t)oc * 20736 + (size_t)icq * 64 * 81;
  for (int idx = t; idx < 5184; idx += 256) {
    const int ici = idx / 81, kk = idx - ici * 81;
    tile[ici * 83 + kk] = src[idx];
  }
  __syncthreads();
  f16* dst = wt + (size_t)oc * 20736 + icq * 64;
  for (int idx = t; idx < 5184; idx += 256) {
    const int kk = idx >> 6, ici = idx & 63;
    dst[kk * 256 + ici] = (f16)tile[ici * 83 + kk];
  }
}

// ---------------- primary caps conv: MFMA implicit GEMM --------------------
// 1152 blocks = 144 mb x 2 nb x 4 ks. Double-buffered: buf0 = sm[0..8192)B,
// buf1 = sm[16384..32768)B interleaved A|B per buffer. Loop: sync; stage
// (s+1)->other buf; consume current buf. One barrier per stage; each drain
// waits on loads issued ~one consume earlier.
__global__ __launch_bounds__(256) void prim_mfma_kernel(
    const f16* __restrict__ ht, const f16* __restrict__ wt,
    float* __restrict__ part)
{
  __shared__ f16 sm[16384];           // 32 KB: [buf][A|B][2048 f16/wave]
  const int t = threadIdx.x;
  const int wv = t >> 6, lane = t & 63;
  const int id = blockIdx.x;
  const int g = id >> 3;              // [0,144)
  const int ks = g & 3;
  const int nb = (g >> 2) & 1;
  const int mb = (id & 7) + 8 * (g >> 3);
  const int m0 = mb * 128, n0 = nb * 128;

  const int chunk = (lane & 3) ^ ((lane >> 3) & 3);
  long aoff[2], boff[2];
#pragma unroll
  for (int i = 0; i < 2; ++i) {
    const int r = wv * 32 + i * 16 + (lane >> 2);  // local row in tile
    const int m = m0 + r;
    const int b = m / 36, pos = m - b * 36;
    const int oy = pos / 6, ox = pos - oy * 6;
    aoff[i] = (long)(((b * 20 + 2 * oy) * 20 + 2 * ox) * 256) * 2 + chunk * 16;
    boff[i] = (long)(n0 + r) * 41472 + chunk * 16;   // oc*81*256*2
  }
  const char* htc = (const char*)ht;
  const char* wtc = (const char*)wt;

  const int lrow = lane & 15, quad = lane >> 4;
  const int qx = quad ^ ((lrow >> 1) & 3);
  const int wm = wv & 1, wn = wv >> 1;
  f32x4 acc[4][4] = {};

  const int s0 = ks * 162, s1 = s0 + 162;   // 162 stages (even), 81 iters

#define STAGE(S, BUFB)                                                        \
  {                                                                           \
    const int kykx = (S) >> 3, icb = (S) & 7;                                 \
    const int ky = kykx / 9, kx = kykx - ky * 9;                              \
    const long astep = (long)((((ky * 20 + kx) * 256) + icb * 32) * 2);       \
    const long bstep = (long)(((kykx * 256) + icb * 32) * 2);                 \
    char* dA = (char*)sm + (BUFB) + wv * 2048;                                \
    char* dB = (char*)sm + (BUFB) + 8192 + wv * 2048;                         \
    gl_lds16(htc + aoff[0] + astep, dA);                                      \
    gl_lds16(htc + aoff[1] + astep, dA + 1024);                               \
    gl_lds16(wtc + boff[0] + bstep, dB);                                      \
    gl_lds16(wtc + boff[1] + bstep, dB + 1024);                               \
  }

#define CONSUME(BUFI)                                                         \
  {                                                                           \
    const f16* As = sm + (BUFI);                                              \
    const f16* Bs = sm + (BUFI) + 4096;                                       \
    f16x8 af[4], bf[4];                                                       \
    _Pragma("unroll") for (int mt = 0; mt < 4; ++mt)                          \
        af[mt] = *(const f16x8*)&As[(wm * 64 + mt * 16 + lrow) * 32 + qx * 8];\
    _Pragma("unroll") for (int nt = 0; nt < 4; ++nt)                          \
        bf[nt] = *(const f16x8*)&Bs[(wn * 64 + nt * 16 + lrow) * 32 + qx * 8];\
    _Pragma("unroll") for (int mt = 0; mt < 4; ++mt)                          \
        _Pragma("unroll") for (int nt = 0; nt < 4; ++nt)                      \
            acc[mt][nt] = __builtin_amdgcn_mfma_f32_16x16x32_f16(             \
                af[mt], bf[nt], acc[mt][nt], 0, 0, 0);                        \
  }

  STAGE(s0, 0);
  for (int s = s0; s < s1; s += 2) {
    __syncthreads();                  // drains buf0 loads (issued 1 consume ago)
    STAGE(s + 1, 16384);              // next loads fly during CONSUME(buf0)
    CONSUME(0);
    __syncthreads();                  // drains buf1 loads
    if (s + 2 < s1) STAGE(s + 2, 0);
    CONSUME(8192);
  }
#undef STAGE
#undef CONSUME

  // epilogue: partials [m][col'] with col' = (oc&31)*8 + oc>>5 (squash reads
  // its 8 values oc = i*32+cc contiguously).
  float* pp = part + (size_t)ks * 4718592;
#pragma unroll
  for (int mt = 0; mt < 4; ++mt) {
    const int mbase = m0 + wm * 64 + mt * 16 + quad * 4;  // row=quad*4+reg
#pragma unroll
    for (int nt = 0; nt < 4; ++nt) {
      const int n = n0 + wn * 64 + nt * 16 + lrow;        // col=lane&15
      const int np = (n & 31) * 8 + (n >> 5);
#pragma unroll
      for (int rg = 0; rg < 4; ++rg)
        pp[(size_t)(mbase + rg) * 256 + np] = acc[mt][nt][rg];
    }
  }
}

// --------- split-K(4) reduce + bias + squash -> u[512,1152,8] fp32 ---------
__global__ void squash_kernel(const float* __restrict__ part,
                              const float* __restrict__ bias,
                              float* __restrict__ u)
{
  const int tid = blockIdx.x * 256 + threadIdx.x;   // (b*36+pos)*32 + cc
  if (tid >= 512 * 36 * 32) return;
  const int cc = tid & 31;
  const int row = tid >> 5;                         // b*36 + pos
  const int b = row / 36;
  const int pos = row - b * 36;
  const float* p = part + (size_t)row * 256 + cc * 8;
  float v[8] = {};
#pragma unroll
  for (int ksl = 0; ksl < 4; ++ksl) {
    const float4 a0 = *(const float4*)(p + (size_t)ksl * 4718592);
    const float4 a1 = *(const float4*)(p + (size_t)ksl * 4718592 + 4);
    v[0] += a0.x; v[1] += a0.y; v[2] += a0.z; v[3] += a0.w;
    v[4] += a1.x; v[5] += a1.y; v[6] += a1.z; v[7] += a1.w;
  }
  float sq = 0.f;
#pragma unroll
  for (int i = 0; i < 8; ++i) {
    v[i] += bias[i * 32 + cc];
    sq = fmaf(v[i], v[i], sq);
  }
  const float scale = sq / ((1.f + sq) * sqrtf(sq));
  float* up = &u[(size_t)(b * 1152 + cc * 36 + pos) * 8];
#pragma unroll
  for (int i = 0; i < 8; ++i) up[i] = v[i] * scale;
}

// --------- priors: P[c,b,r,16] fp16 = einsum('bri,crio') -------------------
__global__ __launch_bounds__(256, 4) void priors_kernel(
    const float* __restrict__ u, const float* __restrict__ rw,
    f16* __restrict__ P)
{
  const int t = threadIdx.x;
  const int rl = t >> 2, oq = t & 3;
  const int r = blockIdx.x * 64 + rl;
  const int b0 = blockIdx.y * 64;
  const int c = blockIdx.z;

  float4 wreg[8];
  const float* wbase = rw + (size_t)(c * 1152 + r) * 128 + oq * 4;
#pragma unroll
  for (int k = 0; k < 8; ++k)
    wreg[k] = *(const float4*)(wbase + k * 16);

  f16* pbase = P + (size_t)((c * 512 + b0) * 1152 + r) * 16 + oq * 4;
  const float* ubase = u + (size_t)(b0 * 1152 + r) * 8;

  for (int b = 0; b < 64; ++b) {
    const float4 ua = *(const float4*)(ubase + (size_t)b * 9216);
    const float4 ub = *(const float4*)(ubase + (size_t)b * 9216 + 4);
    const float uu[8] = {ua.x, ua.y, ua.z, ua.w, ub.x, ub.y, ub.z, ub.w};
    float ax = 0.f, ay = 0.f, az = 0.f, aw = 0.f;
#pragma unroll
    for (int k = 0; k < 8; ++k) {
      ax = fmaf(uu[k], wreg[k].x, ax);
      ay = fmaf(uu[k], wreg[k].y, ay);
      az = fmaf(uu[k], wreg[k].z, az);
      aw = fmaf(uu[k], wreg[k].w, aw);
    }
    f16x4 st;
    st[0] = (f16)ax; st[1] = (f16)ay; st[2] = (f16)az; st[3] = (f16)aw;
    *(f16x4*)(pbase + (size_t)b * 18432) = st;
  }
}

// ---------------- dynamic routing, one block per (c,b) ---------------------
__device__ __forceinline__ float wave_sum(float v) {
#pragma unroll
  for (int off = 32; off > 0; off >>= 1) v += __shfl_xor(v, off);
  return v;
}
__device__ __forceinline__ float wave_max(float v) {
#pragma unroll
  for (int off = 32; off > 0; off >>= 1) v = fmaxf(v, __shfl_xor(v, off));
  return v;
}

__global__ __launch_bounds__(256, 2) void routing_kernel(
    const f16* __restrict__ Pg, float* __restrict__ caps)
{
  const int c = blockIdx.x >> 9;
  const int b = blockIdx.x & 511;
  const int t = threadIdx.x;
  const int wid = t >> 6;
  const int lane = t & 63;
  __shared__ float xred[4 * 17];

  float P[5][16];
  float lg[5];
  const int nk = (t < 128) ? 5 : 4;
#pragma unroll
  for (int k = 0; k < 5; ++k)
#pragma unroll
    for (int o = 0; o < 16; ++o) P[k][o] = 0.f;

  const f16* pbase = Pg + (size_t)((c * 512 + b) * 1152) * 16;
#pragma unroll
  for (int k = 0; k < 5; ++k) {
    if (k < nk) {
      const int r = t + (k << 8);
      const f16x8 p0 = *(const f16x8*)&pbase[(size_t)r * 16];
      const f16x8 p1 = *(const f16x8*)&pbase[(size_t)r * 16 + 8];
#pragma unroll
      for (int o = 0; o < 8; ++o) {
        P[k][o]     = (float)p0[o];
        P[k][o + 8] = (float)p1[o];
      }
    }
  }

  float v[16];
  {
    float sq = 0.f;
#pragma unroll
    for (int o = 0; o < 16; ++o) {
      float p = 0.f;
#pragma unroll
      for (int k = 0; k < 5; ++k) p += P[k][o];
      p = wave_sum(p);
      if (lane == 0) xred[wid * 17 + o] = p;
      v[o] = 0.f;
    }
    __syncthreads();
#pragma unroll
    for (int o = 0; o < 16; ++o) {
      const float s = (xred[o] + xred[17 + o] + xred[34 + o] + xred[51 + o]) *
                      (1.f / 1152.f);
      v[o] = s;
      sq = fmaf(s, s, sq);
    }
    const float scale = sq / ((1.f + sq) * sqrtf(sq));
#pragma unroll
    for (int o = 0; o < 16; ++o) v[o] *= scale;
    __syncthreads();
  }
#pragma unroll
  for (int k = 0; k < 5; ++k) {
    float a = 0.f;
#pragma unroll
    for (int o = 0; o < 16; ++o) a = fmaf(P[k][o], v[o], a);
    lg[k] = a;
  }

  for (int it = 1; it < 3; ++it) {
    float m = -1e30f;
#pragma unroll
    for (int k = 0; k < 5; ++k) if (k < nk) m = fmaxf(m, lg[k]);
    m = wave_max(m);
    if (lane == 0) xred[wid * 17 + 16] = m;
    __syncthreads();
    const float mx = fmaxf(fmaxf(xred[16], xred[17 + 16]),
                           fmaxf(xred[34 + 16], xred[51 + 16]));
    __syncthreads();
    float e[5];
#pragma unroll
    for (int k = 0; k < 5; ++k) e[k] = (k < nk) ? expf(lg[k] - mx) : 0.f;
    float pS = 0.f;
#pragma unroll
    for (int k = 0; k < 5; ++k) pS += e[k];
    pS = wave_sum(pS);
    if (lane == 0) xred[wid * 17 + 16] = pS;
#pragma unroll
    for (int o = 0; o < 16; ++o) {
      float p = 0.f;
#pragma unroll
      for (int k = 0; k < 5; ++k) p = fmaf(e[k], P[k][o], p);
      p = wave_sum(p);
      if (lane == 0) xred[wid * 17 + o] = p;
    }
    __syncthreads();
    const float S = xred[16] + xred[17 + 16] + xred[34 + 16] + xred[51 + 16];
    const float inv = 1.f / S;
    float sq = 0.f;
#pragma unroll
    for (int o = 0; o < 16; ++o) {
      const float s = (xred[o] + xred[17 + o] + xred[34 + o] + xred[51 + o]) * inv;
      v[o] = s;
      sq = fmaf(s, s, sq);
    }
    const float scale = sq / ((1.f + sq) * sqrtf(sq));
#pragma unroll
    for (int o = 0; o < 16; ++o) v[o] *= scale;
    __syncthreads();
    if (it < 2) {
#pragma unroll
      for (int k = 0; k < 5; ++k) {
        float a = 0.f;
#pragma unroll
        for (int o = 0; o < 16; ++o) a = fmaf(P[k][o], v[o], a);
        lg[k] += a;
      }
    }
  }
  if (t == 0) {
    float* cp = &caps[(b * 10 + c) * 16];
#pragma unroll
    for (int o = 0; o < 16; ++o) cp[o] = v[o];
  }
}

// --------- classes softmax + argmax one-hot mask ---------------------------
__global__ void classes_kernel(const float* __restrict__ caps,
                               float* __restrict__ out_classes,
                               float* __restrict__ d0)
{
  const int b = blockIdx.x * 256 + threadIdx.x;
  if (b >= 512) return;
  float nrm[10];
#pragma unroll
  for (int cc = 0; cc < 10; ++cc) {
    float sq = 0.f;
#pragma unroll
    for (int o = 0; o < 16; ++o) {
      const float vv = caps[(b * 10 + cc) * 16 + o];
      sq = fmaf(vv, vv, sq);
    }
    nrm[cc] = sqrtf(sq);
  }
  float mx = nrm[0]; int cs = 0;
#pragma unroll
  for (int cc = 1; cc < 10; ++cc)
    if (nrm[cc] > mx) { mx = nrm[cc]; cs = cc; }
  float e[10], ssum = 0.f;
#pragma unroll
  for (int cc = 0; cc < 10; ++cc) { e[cc] = expf(nrm[cc] - mx); ssum += e[cc]; }
  const float inv = 1.f / ssum;
#pragma unroll
  for (int cc = 0; cc < 10; ++cc) out_classes[b * 10 + cc] = e[cc] * inv;
#pragma unroll
  for (int cc = 0; cc < 10; ++cc)
#pragma unroll
    for (int o = 0; o < 16; ++o)
      d0[b * 160 + cc * 16 + o] = (cc == cs) ? caps[(b * 10 + cc) * 16 + o] : 0.f;
}

// --------- decoder GEMM: C[M,N] = act(A[M,K] @ W[N,K]^T + bias) ------------
__global__ __launch_bounds__(256, 2) void fc_kernel(
    const float* __restrict__ A, const float* __restrict__ W,
    const float* __restrict__ bias, float* __restrict__ C,
    int N, int K, int act)
{
  __shared__ float As[64][17];
  __shared__ float Ws[64][17];
  const int t = threadIdx.x;
  const int tm = t >> 4, tn = t & 15;
  const int m0 = blockIdx.y << 6, n0 = blockIdx.x << 6;
  const int lr = t >> 2, lq = (t & 3) << 2;
  float acc[4][4] = {};
  for (int k0 = 0; k0 < K; k0 += 16) {
    const float4 av = *(const float4*)&A[(m0 + lr) * K + k0 + lq];
    float4 wv = make_float4(0.f, 0.f, 0.f, 0.f);
    const int wn = n0 + lr;
    if (wn < N) wv = *(const float4*)&W[wn * K + k0 + lq];
    __syncthreads();
    As[lr][lq+0] = av.x; As[lr][lq+1] = av.y; As[lr][lq+2] = av.z; As[lr][lq+3] = av.w;
    Ws[lr][lq+0] = wv.x; Ws[lr][lq+1] = wv.y; Ws[lr][lq+2] = wv.z; Ws[lr][lq+3] = wv.w;
    __syncthreads();
#pragma unroll
    for (int kk = 0; kk < 16; ++kk) {
      float a[4], w[4];
#pragma unroll
      for (int i = 0; i < 4; ++i) a[i] = As[tm * 4 + i][kk];
#pragma unroll
      for (int j = 0; j < 4; ++j) w[j] = Ws[tn * 4 + j][kk];
#pragma unroll
      for (int i = 0; i < 4; ++i)
#pragma unroll
        for (int j = 0; j < 4; ++j) acc[i][j] = fmaf(a[i], w[j], acc[i][j]);
    }
  }
#pragma unroll
  for (int i = 0; i < 4; ++i) {
    const int m = m0 + tm * 4 + i;
#pragma unroll
    for (int j = 0; j < 4; ++j) {
      const int n = n0 + tn * 4 + j;
      if (n < N) {
        float vv = acc[i][j] + bias[n];
        vv = act ? (1.f / (1.f + expf(-vv))) : fmaxf(vv, 0.f);
        C[m * N + n] = vv;
      }
    }
  }
}

// ============================================================================
extern "C" void kernel_launch(void* const* d_in, const int* in_sizes, int n_in,
                              void* d_out, int out_size, void* d_ws, size_t ws_size,
                              hipStream_t stream)
{
  const float* x       = (const float*)d_in[0];
  const float* conv1_w = (const float*)d_in[1];
  const float* conv1_b = (const float*)d_in[2];
  const float* prim_w  = (const float*)d_in[3];
  const float* prim_b  = (const float*)d_in[4];
  const float* route_w = (const float*)d_in[5];
  const float* dec_w1  = (const float*)d_in[6];
  const float* dec_b1  = (const float*)d_in[7];
  const float* dec_w2  = (const float*)d_in[8];
  const float* dec_b2  = (const float*)d_in[9];
  const float* dec_w3  = (const float*)d_in[10];
  const float* dec_b3  = (const float*)d_in[11];
  float* out = (float*)d_out;

  char* ws = (char*)d_ws;
  f16*   ht   = (f16*)(ws);                        // 104,857,600 B
  f16*   wtp  = (f16*)(ws + 104857600);            //  10,616,832 B
  float* part = (float*)(ws + 115474432);          //  75,497,472 B (4 slices)
  float* u    = (float*)(ws + 190971904);          //  18,874,368 B
  f16*   P    = (f16*)(ws);                        // 188,743,680 B (overlays)
  float* caps = (float*)(ws + 209846272);          // 327,680 B
  float* d0   = (float*)(ws + 210173952);          // 327,680 B
  float* d1   = (float*)(ws + 210501632);          // 1,048,576 B
  float* d2   = (float*)(ws + 211550208);          // 2,097,152 B

  hipLaunchKernelGGL(conv1_kernel, dim3(512, 4), dim3(256), 0, stream,
                     x, conv1_w, conv1_b, ht);
  hipLaunchKernelGGL(wtrans_kernel, dim3(256, 4), dim3(256), 0, stream,
                     prim_w, wtp);
  hipLaunchKernelGGL(prim_mfma_kernel, dim3(1152), dim3(256), 0, stream,
                     ht, wtp, part);
  hipLaunchKernelGGL(squash_kernel, dim3(2304), dim3(256), 0, stream,
                     part, prim_b, u);
  hipLaunchKernelGGL(priors_kernel, dim3(18, 8, 10), dim3(256), 0, stream,
                     u, route_w, P);
  hipLaunchKernelGGL(routing_kernel, dim3(5120), dim3(256), 0, stream,
                     P, caps);
  hipLaunchKernelGGL(classes_kernel, dim3(2), dim3(256), 0, stream,
                     caps, out, d0);
  hipLaunchKernelGGL(fc_kernel, dim3(8, 8), dim3(256), 0, stream,
                     d0, dec_w1, dec_b1, d1, 512, 160, 0);
  hipLaunchKernelGGL(fc_kernel, dim3(16, 8), dim3(256), 0, stream,
                     d1, dec_w2, dec_b2, d2, 1024, 512, 0);
  hipLaunchKernelGGL(fc_kernel, dim3(13, 8), dim3(256), 0, stream,
                     d2, dec_w3, dec_b3, out + 5120, 784, 1024, 1);
}